// Round 3
// baseline (234.305 us; speedup 1.0000x reference)
//
#include <hip/hip_runtime.h>

// ---------------------------------------------------------------------------
// MatchNet: 3-layer MLP (relu after every layer) -> batched PDHG LP solve.
// Shapes: X[2048,64], W1[64,1024], W2[1024,1024], W3[1024,512], S[64,512].
// Output: x [2048,512] fp32.
//
// R18: 2-barrier PDHG via sv-independent delta split.
//   Delta-xbar_i = u1 + 2 sv_i d_i with u1 = 2z - x_{i-1} - xb_{i-1}:
//   interval 2 writes {u1, d, red} at ONE barrier; interval 1 reads red -> sv,
//   combines the Kx A-frag in-register (v_pk_fma_f16, sv is per-row = per-lane
//   scalar on A-frags), does the deferred x/xbar update, Kx, y-update, dy.
//   3 cross-wave exchanges now ride on 2 barriers (R16/17 had 3; chain-bound
//   evidence: R17 doubled occupancy+MFMA, conflicts -4.5x, yet 91.5->107.5us).
//   8-row blocks, 256 blocks (R17's 4-row split reverted). RTN casts for u1/d.
//   Epilogue applies the 60th x-update. prep s1f colmap back to pi'.
// GEMMs / power_64 unchanged.
// ---------------------------------------------------------------------------

typedef _Float16 half8 __attribute__((ext_vector_type(8)));
typedef __fp16 fp16x2 __attribute__((ext_vector_type(2)));
typedef __fp16 fp16x4 __attribute__((ext_vector_type(4)));
typedef float floatx4 __attribute__((ext_vector_type(4)));
typedef float floatx2 __attribute__((ext_vector_type(2)));

#define BATCH 2048
#define NITERS 60
#define XBS 520   // u1/d LDS row stride in halves (1040B; 1040 mod 128 = 16)
#define YLS 72    // dy LDS row stride in halves (144B; 144 mod 128 = 16)

typedef const __attribute__((address_space(1))) unsigned int* gptr_as1;
typedef __attribute__((address_space(3))) unsigned int* lptr_as3;
__device__ __forceinline__ void gl_lds16(const _Float16* g, _Float16* s) {
    __builtin_amdgcn_global_load_lds((gptr_as1)g, (lptr_as3)s, 16, 0, 0);
}

// ---- cross-lane sums: DPP (VALU pipe) within 16-lane rows ----
template <int CTRL>
__device__ __forceinline__ float dpp_addf(float x) {
    int y = __builtin_amdgcn_update_dpp(0, __builtin_bit_cast(int, x), CTRL, 0xf, 0xf, true);
    return x + __builtin_bit_cast(float, y);
}
__device__ __forceinline__ float sum16(float x) {
    x = dpp_addf<0xB1>(x);    // quad_perm(1,0,3,2): xor 1
    x = dpp_addf<0x4E>(x);    // quad_perm(2,3,0,1): xor 2
    x = dpp_addf<0x124>(x);   // row_ror:4
    x = dpp_addf<0x128>(x);   // row_ror:8 -> full 16-lane sum in all lanes
    return x;
}
__device__ __forceinline__ float sum64(float x) {
    x = sum16(x);
    x += __builtin_bit_cast(float, __builtin_amdgcn_ds_swizzle(__builtin_bit_cast(int, x), 0x401F)); // xor16
    x += __shfl_xor(x, 32, 64);   // cross-half combine
    return x;
}

// ---------------- 64-dim power iteration for tau (one 256-thread block) --------
__device__ void power_64(const float* __restrict__ S, float* __restrict__ tau_g) {
    __shared__ unsigned long long rowm[64][8];   // row bitmasks of S
    __shared__ float G[64][65];                  // Gram, +1 pad (conflict-free)
    __shared__ float wl[64], pg[4][64];
    int t = threadIdx.x, wv = t >> 6, ln = t & 63;
    for (int rr = 0; rr < 16; rr++) {
        int r = wv * 16 + rr;
        float v[8];
#pragma unroll
        for (int e = 0; e < 8; e++) v[e] = S[r * 512 + e * 64 + ln];
#pragma unroll
        for (int e = 0; e < 8; e++) {
            unsigned long long m = __ballot(v[e] != 0.f);
            if (ln == 0) rowm[r][e] = m;
        }
    }
    __syncthreads();
    for (int k = 0; k < 16; k++) {
        int idx = t * 16 + k;
        int i = idx >> 6, j = idx & 63;
        int cnt = 0;
#pragma unroll
        for (int e = 0; e < 8; e++) cnt += __popcll(rowm[i][e] & rowm[j][e]);
        G[i][j] = (float)cnt;
    }
    if (wv == 0) {   // w0 = S v0 = rowcount/sqrt(512)
        int cnt = 0;
#pragma unroll
        for (int e = 0; e < 8; e++) cnt += __popcll(rowm[ln][e]);
        wl[ln] = (float)cnt * 0.044194173824159216f;
    }
    __syncthreads();
    for (int s = 0; s < 30; s++) {
        float a = 0.f;
#pragma unroll
        for (int jj = 0; jj < 16; jj++) {
            int j = wv * 16 + jj;
            a += G[ln][j] * wl[j];
        }
        pg[wv][ln] = a;
        __syncthreads();
        if (wv == 0) {
            float g = (pg[0][ln] + pg[1][ln]) + (pg[2][ln] + pg[3][ln]);
            float wi = wl[ln];
            float s1 = sum64(wi * g);
            float s2 = sum64(wi * wi);
            float n = sqrtf(s1 + 2.f * s2 + 1.f);
            wl[ln] = (g + wi) / n;
        }
        __syncthreads();
    }
    if (wv == 0) {
        float wi = wl[ln];
        float s2 = sum64(wi * wi);
        if (ln == 0) tau_g[0] = 0.9f / sqrtf(s2 + 1.f);
    }
}

// ---------------- merged prep: cast X, W transposes, S frags -------------------
__global__ __launch_bounds__(256) void prep(
    const float* __restrict__ X, _Float16* __restrict__ Xh,
    const float* __restrict__ W1, _Float16* __restrict__ W1t,
    const float* __restrict__ W2, _Float16* __restrict__ W2t,
    const float* __restrict__ W3, _Float16* __restrict__ W3t,
    const float* __restrict__ S, _Float16* __restrict__ s1f,
    _Float16* __restrict__ s2f) {
    __shared__ float tile[32][33];
    int tid = threadIdx.x;
    int bid = blockIdx.x;
    if (bid < 512) {
        int i = bid * 256 + tid;
        Xh[i] = (_Float16)X[i];
        return;
    }
    bid -= 512;
    if (bid < 1600) {   // transpose+cast W[K][N] -> Wt[N][K]
        const float* W; _Float16* Wt; int K, N, b;
        if (bid < 64)        { W = W1; Wt = W1t; K = 64;   N = 1024; b = bid; }
        else if (bid < 1088) { W = W2; Wt = W2t; K = 1024; N = 1024; b = bid - 64; }
        else                 { W = W3; Wt = W3t; K = 1024; N = 512;  b = bid - 1088; }
        int nbx = N / 32;
        int n0 = (b % nbx) * 32, k0 = (b / nbx) * 32;
        int tx = tid & 31, ty = tid >> 5;
#pragma unroll
        for (int i = 0; i < 4; i++)
            tile[ty + i * 8][tx] = W[(size_t)(k0 + ty + i * 8) * N + n0 + tx];
        __syncthreads();
#pragma unroll
        for (int i = 0; i < 4; i++)
            Wt[(size_t)(n0 + ty + i * 8) * K + k0 + tx] = (_Float16)tile[tx][ty + i * 8];
        return;
    }
    bid -= 1600;
    int i = bid * 256 + tid;       // 0 .. 65535
    if (i < 4 * 16 * 64 * 8) {     // s1f: B-frag of S^T, k-axis in pi'-order
        int j = i & 7, lane = (i >> 3) & 63, kk = (i >> 9) & 15, wc = i >> 13;
        int pos = kk * 32 + (lane >> 4) * 8 + j;   // storage k position 0..511
        int pp = pos >> 7, r = pos & 127;
        int hh = r >> 6, r2 = r & 63;
        int lmc = r2 >> 2, t3 = r2 & 3;
        int c = pp * 128 + (hh * 4 + t3) * 16 + lmc;   // pi'^-1
        int m = wc * 16 + (lane & 15);
        s1f[i] = (_Float16)S[m * 512 + c];
    } else {                       // s2f: B-frag of S (k = combos)
        int i2 = i - 4 * 16 * 64 * 8;
        int j = i2 & 7, lane = (i2 >> 3) & 63, c = (i2 >> 9) & 1,
            tt = (i2 >> 10) & 7, wc = i2 >> 13;
        int kc = c * 32 + (lane >> 4) * 8 + j;
        int n = wc * 128 + tt * 16 + (lane & 15);
        s2f[i2] = (_Float16)S[kc * 512 + n];
    }
}

// ---------------- GEMM: out = relu(A[M,K] @ W[K,N] + bias), f16 in, fp32 acc ---
__global__ __launch_bounds__(256) void gemm_relu(
    const _Float16* __restrict__ A, const _Float16* __restrict__ Wt,
    const float* __restrict__ bias, _Float16* __restrict__ outh,
    float* __restrict__ outf, int N, int K,
    const float* __restrict__ Sp, float* __restrict__ tau_g) {
    __shared__ __align__(16) _Float16 As[128 * 32];
    __shared__ __align__(16) _Float16 Bs[64 * 32];
    int tid = threadIdx.x;
    int bm = blockIdx.y * 128;
    int bn = blockIdx.x * 64;
    if (bn >= N) {
        if (blockIdx.y == 0 && Sp) power_64(Sp, tau_g);
        return;
    }
    int w = tid >> 6, l = tid & 63;
    int wr = w >> 1, wc = w & 1;
    int lm = l & 15, q = l >> 4;
    floatx4 acc[4][2] = {};

    int sr = l >> 2;
    int sc = (l & 3) * 8;
    const _Float16* ag0 = A + (size_t)(bm + w * 32 + sr) * K + sc;
    const _Float16* ag1 = A + (size_t)(bm + w * 32 + 16 + sr) * K + sc;
    _Float16* as0 = &As[(w * 32) * 32];
    _Float16* as1 = &As[(w * 32 + 16) * 32];
    const _Float16* bg = Wt + (size_t)(bn + w * 16 + sr) * K + sc;
    _Float16* bs = &Bs[(w * 16) * 32];

    for (int k0 = 0; k0 < K; k0 += 32) {
        gl_lds16(ag0 + k0, as0);
        gl_lds16(ag1 + k0, as1);
        gl_lds16(bg + k0, bs);
        __syncthreads();
        half8 af[4], bf[2];
#pragma unroll
        for (int mt = 0; mt < 4; mt++)
            af[mt] = *(const half8*)&As[(wr * 64 + mt * 16 + lm) * 32 + q * 8];
#pragma unroll
        for (int nt = 0; nt < 2; nt++)
            bf[nt] = *(const half8*)&Bs[(wc * 32 + nt * 16 + lm) * 32 + q * 8];
#pragma unroll
        for (int mt = 0; mt < 4; mt++)
#pragma unroll
            for (int nt = 0; nt < 2; nt++)
                acc[mt][nt] = __builtin_amdgcn_mfma_f32_16x16x32_f16(
                    af[mt], bf[nt], acc[mt][nt], 0, 0, 0);
        __syncthreads();
    }
#pragma unroll
    for (int nt = 0; nt < 2; nt++) {
        int col = bn + wc * 32 + nt * 16 + lm;
        float bv = bias[col];
#pragma unroll
        for (int mt = 0; mt < 4; mt++) {
#pragma unroll
            for (int v = 0; v < 4; v++) {
                int row = bm + wr * 64 + mt * 16 + q * 4 + v;
                float val = fmaxf(acc[mt][nt][v] + bv, 0.f);
                if (outh) outh[(size_t)row * N + col] = (_Float16)val;
                else      outf[(size_t)row * N + col] = val;
            }
        }
    }
}

// ---------------- 2-barrier delta-split MFMA PDHG, 4 waves, 8 rows -------------
// Wave p owns columns [p*128, p*128+128). Lane l: lm=l&15, q=l>>4.
// (qa=q&1, h=q>>1): lane owns rows qa*4+v (v=0..3) x cols (h*4+t)*16+lm (t=0..3).
// LDS tiles have 8 REAL rows; MFMA A-frags read row lq=lm&7 (2-way broadcast).
// Interval 1: red->sv, deferred x/xbar update, A-frag = u1 + 2sv[row]*d
//             (pk_fma), Kx MFMA, y-update, dy write.          [barrier]
// Interval 2: KTy MFMA, elementwise -> d, u1 = 2z-x-xb, write u1/d (RTN),
//             norm partials -> red.                            [barrier]
__global__ __launch_bounds__(256, 1) void pdhg_mfma(
    const float* __restrict__ Zb, const float* __restrict__ Xf,
    const _Float16* __restrict__ s1f, const _Float16* __restrict__ s2f,
    const float* __restrict__ tau_p, float* __restrict__ out) {
    __shared__ __align__(16) _Float16 u1_d[8 * XBS];
    __shared__ __align__(16) _Float16 dd_d[8 * XBS];
    __shared__ __align__(16) _Float16 yl_d[8 * YLS];
    __shared__ __align__(16) float red[8][4];
    int tid = threadIdx.x;
    int p = tid >> 6;                 // wave = column slice
    int l = tid & 63, lm = l & 15, q = l >> 4;
    int lq = lm & 7;                  // 8-row A-frag read index (broadcast pairs)
    int qa = q & 1, h = q >> 1;
    int b0 = blockIdx.x * 8;

    half8 s1[16], s2[8][2];
#pragma unroll
    for (int k = 0; k < 16; k++)
        s1[k] = *(const half8*)&s1f[((p * 16 + k) * 64 + l) * 8];
#pragma unroll
    for (int u = 0; u < 8; u++)
#pragma unroll
        for (int c = 0; c < 2; c++)
            s2[u][c] = *(const half8*)&s2f[(((p * 8 + u) * 2 + c) * 64 + l) * 8];

    floatx4 z4[4], tz4[4], x4[4], xb4[4], yh4[4], d4[4];
    floatx4 ylo = {}, Bc;
    floatx4 a1p[4] = {};
    floatx4 acc2[8] = {};
    const floatx4 zero4 = {0.f, 0.f, 0.f, 0.f};
    float tau = tau_p[0];
    float sig = tau;

#pragma unroll
    for (int v = 0; v < 4; v++)
        Bc[v] = Xf[(b0 + qa * 4 + v) * 64 + p * 16 + lm];
#pragma unroll
    for (int t = 0; t < 4; t++) {
#pragma unroll
        for (int v = 0; v < 4; v++) {
            float zz = Zb[(size_t)(b0 + qa * 4 + v) * 512 + p * 128 + (h * 4 + t) * 16 + lm];
            z4[t][v] = zz;
            tz4[t][v] = tau - zz;
        }
        x4[t] = zero4; xb4[t] = zero4; yh4[t] = zero4; d4[t] = zero4;
    }
    {
        half8 hz = {0, 0, 0, 0, 0, 0, 0, 0};
        for (int i = tid; i < (8 * XBS) / 8; i += 256) {
            *(half8*)&u1_d[i * 8] = hz;
            *(half8*)&dd_d[i * 8] = hz;
        }
        if (tid < 32) ((float*)red)[tid] = 0.f;
    }
    __syncthreads();

#pragma unroll 1
    for (int it = 0; it < NITERS; ++it) {
        // ---------------- interval 1 ----------------
        floatx4 rra = *(const floatx4*)&red[lq][0];
        float n2a = (rra.x + rra.y) + (rra.z + rra.w);
        float sva = fmaxf(1.f - tau * rsqrtf(fmaxf(n2a, 1e-24f)), 0.f);
        _Float16 svh = (_Float16)(2.f * sva);
        half8 svb = {svh, svh, svh, svh, svh, svh, svh, svh};
        if (it) {   // deferred x/xbar update for iter it (uses sv from red)
            floatx4 sv4;
#pragma unroll
            for (int v = 0; v < 4; v++) {
                floatx4 rr = *(const floatx4*)&red[qa * 4 + v][0];
                float n2 = (rr.x + rr.y) + (rr.z + rr.w);
                sv4[v] = fmaxf(1.f - tau * rsqrtf(fmaxf(n2, 1e-24f)), 0.f);
            }
#pragma unroll
            for (int t = 0; t < 4; t++) {
                floatx4 xn = z4[t] + sv4 * d4[t];
                xb4[t] = 2.f * xn - x4[t];
                x4[t] = xn;
            }
        }
        // Kx: A-frag = u1 + 2sv[row]*d (per-lane row = lq), delta-accumulated
#pragma unroll
        for (int k = 0; k < 16; k++) {
            half8 uh = *(const half8*)&u1_d[lq * XBS + k * 32 + q * 8];
            half8 dh = *(const half8*)&dd_d[lq * XBS + k * 32 + q * 8];
            half8 af = uh + svb * dh;
            a1p[k & 3] = __builtin_amdgcn_mfma_f32_16x16x32_f16(af, s1[k], a1p[k & 3], 0, 0, 0);
        }
        floatx4 a1 = (a1p[0] + a1p[1]) + (a1p[2] + a1p[3]);
        floatx4 yv = __builtin_elementwise_max(ylo + sig * (a1 - Bc), zero4);
        floatx4 dy = yv - ylo;
        ylo = yv;
        if (q < 2) {
#pragma unroll
            for (int v = 0; v < 4; v++)
                yl_d[(q * 4 + v) * YLS + p * 16 + lm] = (_Float16)dy[v];
        }
        __syncthreads();   // [A]
        // ---------------- interval 2 ----------------
        half8 a2d[2];
#pragma unroll
        for (int c = 0; c < 2; c++)
            a2d[c] = *(const half8*)&yl_d[lq * YLS + c * 32 + q * 8];
#pragma unroll
        for (int u = 0; u < 8; u++)
#pragma unroll
            for (int c = 0; c < 2; c++)
                acc2[u] = __builtin_amdgcn_mfma_f32_16x16x32_f16(a2d[c], s2[u][c], acc2[u], 0, 0, 0);
        floatx4 pn = {};
        floatx4 u1t[4];
#pragma unroll
        for (int t = 0; t < 4; t++) {
            floatx4 accs = h ? acc2[4 + t] : acc2[t];
            yh4[t] = __builtin_elementwise_max(yh4[t] - sig * xb4[t], zero4);
            floatx4 kty = accs - yh4[t];
            floatx4 ddv = (x4[t] - tau * kty) + tz4[t];
            d4[t] = ddv;
            pn += ddv * ddv;
            u1t[t] = (z4[t] - x4[t]) + (z4[t] - xb4[t]);
        }
        // write u1, d (RTN casts) at pi'(row, p, h, lm, t): contiguous fp16x4
#pragma unroll
        for (int v = 0; v < 4; v++) {
            fp16x4 hu = {(__fp16)u1t[0][v], (__fp16)u1t[1][v], (__fp16)u1t[2][v], (__fp16)u1t[3][v]};
            fp16x4 hd = {(__fp16)d4[0][v], (__fp16)d4[1][v], (__fp16)d4[2][v], (__fp16)d4[3][v]};
            int adr = (qa * 4 + v) * XBS + p * 128 + h * 64 + lm * 4;
            *(fp16x4*)&u1_d[adr] = hu;
            *(fp16x4*)&dd_d[adr] = hd;
        }
        // row-norm partials: 16 lanes (DPP) + h-partner (xor32) -> red[row][p]
#pragma unroll
        for (int v = 0; v < 4; v++) pn[v] = sum16(pn[v]);
#pragma unroll
        for (int v = 0; v < 4; v++) pn[v] += __shfl_xor(pn[v], 32, 64);
        if (lm == 0 && q < 2) {
#pragma unroll
            for (int v = 0; v < 4; v++) red[q * 4 + v][p] = pn[v];
        }
        __syncthreads();   // [B]
    }
    // epilogue: apply the 60th x-update and store
    floatx4 sv4;
#pragma unroll
    for (int v = 0; v < 4; v++) {
        floatx4 rr = *(const floatx4*)&red[qa * 4 + v][0];
        float n2 = (rr.x + rr.y) + (rr.z + rr.w);
        sv4[v] = fmaxf(1.f - tau * rsqrtf(fmaxf(n2, 1e-24f)), 0.f);
    }
#pragma unroll
    for (int t = 0; t < 4; t++) {
        floatx4 xn = z4[t] + sv4 * d4[t];
#pragma unroll
        for (int v = 0; v < 4; v++)
            out[(size_t)(b0 + qa * 4 + v) * 512 + p * 128 + (h * 4 + t) * 16 + lm] = xn[v];
    }
}

// ---------------------------------------------------------------------------
extern "C" void kernel_launch(void* const* d_in, const int* in_sizes, int n_in,
                              void* d_out, int out_size, void* d_ws, size_t ws_size,
                              hipStream_t stream) {
    const float* X  = (const float*)d_in[0];
    const float* W1 = (const float*)d_in[1];
    const float* b1 = (const float*)d_in[2];
    const float* W2 = (const float*)d_in[3];
    const float* b2 = (const float*)d_in[4];
    const float* W3 = (const float*)d_in[5];
    const float* b3 = (const float*)d_in[6];
    const float* S  = (const float*)d_in[7];
    float* out = (float*)d_out;

    char* ws = (char*)d_ws;
    size_t off = 0;
    auto alloc = [&](size_t bytes) {
        void* p = ws + off;
        off += (bytes + 255) & ~(size_t)255;
        return p;
    };
    _Float16* Xh  = (_Float16*)alloc((size_t)BATCH * 64 * 2);
    _Float16* W1t = (_Float16*)alloc((size_t)64 * 1024 * 2);
    _Float16* W2t = (_Float16*)alloc((size_t)1024 * 1024 * 2);
    _Float16* W3t = (_Float16*)alloc((size_t)1024 * 512 * 2);
    _Float16* H1  = (_Float16*)alloc((size_t)BATCH * 1024 * 2);
    _Float16* H2  = (_Float16*)alloc((size_t)BATCH * 1024 * 2);
    float*    Zb  = (float*)alloc((size_t)BATCH * 512 * 4);
    _Float16* s1f = (_Float16*)alloc((size_t)4 * 16 * 64 * 8 * 2);
    _Float16* s2f = (_Float16*)alloc((size_t)4 * 8 * 2 * 64 * 8 * 2);
    float*    tau = (float*)alloc(256);

    hipLaunchKernelGGL(prep, dim3(2368), dim3(256), 0, stream,
                       X, Xh, W1, W1t, W2, W2t, W3, W3t, S, s1f, s2f);
    hipLaunchKernelGGL(gemm_relu, dim3(16, 16), dim3(256), 0, stream,
                       Xh, W1t, b1, H1, (float*)nullptr, 1024, 64,
                       (const float*)nullptr, (float*)nullptr);
    hipLaunchKernelGGL(gemm_relu, dim3(17, 16), dim3(256), 0, stream,
                       H1, W2t, b2, H2, (float*)nullptr, 1024, 1024, S, tau);
    hipLaunchKernelGGL(gemm_relu, dim3(8, 16), dim3(256), 0, stream,
                       H2, W3t, b3, (_Float16*)nullptr, Zb, 512, 1024,
                       (const float*)nullptr, (float*)nullptr);
    hipLaunchKernelGGL(pdhg_mfma, dim3(BATCH / 8), dim3(256), 0, stream,
                       Zb, X, s1f, s2f, tau, out);
}

// Round 4
// 203.913 us; speedup vs baseline: 1.1490x; 1.1490x over previous
//
#include <hip/hip_runtime.h>

// ---------------------------------------------------------------------------
// MatchNet: 3-layer MLP (relu after every layer) -> batched PDHG LP solve.
// Shapes: X[2048,64], W1[64,1024], W2[1024,1024], W3[1024,512], S[64,512].
// Output: x [2048,512] fp32.
//
// R19: pdhg_mfma reverted EXACTLY to R16 (91.5us best; R17/R18 restructures
// both regressed -> 3-barrier/4-wave shape is the pdhg local optimum).
// GEMMs retiled: 64x64 tiles, 256 thr, launch_bounds(256,2):
//  - gemm1/gemm2: 512 blocks = 2 blocks/CU (cross-block latency hiding;
//    they were 1 block/CU single-buffered = fully exposed staging latency).
//  - gemm3: 128 -> 256 blocks (was leaving HALF the CUs idle).
//  - both-sides XOR swizzle (mask ((row>>1)&7)<<4 bytes): pre-swizzled
//    GLOBAL source per-lane keeps global_load_lds dest linear (rule #21),
//    read-side XOR makes frag ds_read_b128 <=2-way banked (was 8-way).
// prep / power_64 unchanged.
// ---------------------------------------------------------------------------

typedef _Float16 half8 __attribute__((ext_vector_type(8)));
typedef __fp16 fp16x2 __attribute__((ext_vector_type(2)));
typedef __fp16 fp16x4 __attribute__((ext_vector_type(4)));
typedef float floatx4 __attribute__((ext_vector_type(4)));
typedef float floatx2 __attribute__((ext_vector_type(2)));

#define BATCH 2048
#define NITERS 60
#define XBS 520   // delta-xbar LDS row stride in halves
#define YLS 72    // delta-ylo  LDS row stride in halves

typedef const __attribute__((address_space(1))) unsigned int* gptr_as1;
typedef __attribute__((address_space(3))) unsigned int* lptr_as3;
__device__ __forceinline__ void gl_lds16(const _Float16* g, _Float16* s) {
    __builtin_amdgcn_global_load_lds((gptr_as1)g, (lptr_as3)s, 16, 0, 0);
}

// ---- cross-lane sums: DPP (VALU pipe) within 16-lane rows ----
template <int CTRL>
__device__ __forceinline__ float dpp_addf(float x) {
    int y = __builtin_amdgcn_update_dpp(0, __builtin_bit_cast(int, x), CTRL, 0xf, 0xf, true);
    return x + __builtin_bit_cast(float, y);
}
__device__ __forceinline__ float sum16(float x) {
    x = dpp_addf<0xB1>(x);    // quad_perm(1,0,3,2): xor 1
    x = dpp_addf<0x4E>(x);    // quad_perm(2,3,0,1): xor 2
    x = dpp_addf<0x124>(x);   // row_ror:4
    x = dpp_addf<0x128>(x);   // row_ror:8 -> full 16-lane sum in all lanes
    return x;
}
__device__ __forceinline__ float sum64(float x) {
    x = sum16(x);
    x += __builtin_bit_cast(float, __builtin_amdgcn_ds_swizzle(__builtin_bit_cast(int, x), 0x401F)); // xor16
    x += __shfl_xor(x, 32, 64);   // cross-half combine
    return x;
}

// ---------------- 64-dim power iteration for tau (one 256-thread block) --------
// Exact reduction of the reference 512-dim recursion: w_k = S v_k;
//   n_k = sqrt(w'Gw + 2|w|^2 + 1);  w_{k+1} = (Gw + w)/n_k;
//   w_0[i] = rowcount_i / sqrt(512);  L = sqrt(|w_30|^2 + 1);  tau = 0.9/L.
__device__ void power_64(const float* __restrict__ S, float* __restrict__ tau_g) {
    __shared__ unsigned long long rowm[64][8];   // row bitmasks of S
    __shared__ float G[64][65];                  // Gram, +1 pad (conflict-free)
    __shared__ float wl[64], pg[4][64];
    int t = threadIdx.x, wv = t >> 6, ln = t & 63;
    for (int rr = 0; rr < 16; rr++) {
        int r = wv * 16 + rr;
        float v[8];
#pragma unroll
        for (int e = 0; e < 8; e++) v[e] = S[r * 512 + e * 64 + ln];
#pragma unroll
        for (int e = 0; e < 8; e++) {
            unsigned long long m = __ballot(v[e] != 0.f);
            if (ln == 0) rowm[r][e] = m;
        }
    }
    __syncthreads();
    for (int k = 0; k < 16; k++) {
        int idx = t * 16 + k;
        int i = idx >> 6, j = idx & 63;
        int cnt = 0;
#pragma unroll
        for (int e = 0; e < 8; e++) cnt += __popcll(rowm[i][e] & rowm[j][e]);
        G[i][j] = (float)cnt;
    }
    if (wv == 0) {   // w0 = S v0 = rowcount/sqrt(512)
        int cnt = 0;
#pragma unroll
        for (int e = 0; e < 8; e++) cnt += __popcll(rowm[ln][e]);
        wl[ln] = (float)cnt * 0.044194173824159216f;
    }
    __syncthreads();
    for (int s = 0; s < 30; s++) {
        float a = 0.f;
#pragma unroll
        for (int jj = 0; jj < 16; jj++) {
            int j = wv * 16 + jj;
            a += G[ln][j] * wl[j];
        }
        pg[wv][ln] = a;
        __syncthreads();
        if (wv == 0) {
            float g = (pg[0][ln] + pg[1][ln]) + (pg[2][ln] + pg[3][ln]);  // (Gw)[ln]
            float wi = wl[ln];
            float s1 = sum64(wi * g);    // w'Gw
            float s2 = sum64(wi * wi);   // |w|^2
            float n = sqrtf(s1 + 2.f * s2 + 1.f);
            wl[ln] = (g + wi) / n;
        }
        __syncthreads();
    }
    if (wv == 0) {
        float wi = wl[ln];
        float s2 = sum64(wi * wi);
        if (ln == 0) tau_g[0] = 0.9f / sqrtf(s2 + 1.f);
    }
}

// ---------------- merged prep: cast X, W transposes, S frags -------------------
__global__ __launch_bounds__(256) void prep(
    const float* __restrict__ X, _Float16* __restrict__ Xh,
    const float* __restrict__ W1, _Float16* __restrict__ W1t,
    const float* __restrict__ W2, _Float16* __restrict__ W2t,
    const float* __restrict__ W3, _Float16* __restrict__ W3t,
    const float* __restrict__ S, _Float16* __restrict__ s1f,
    _Float16* __restrict__ s2f) {
    __shared__ float tile[32][33];
    int tid = threadIdx.x;
    int bid = blockIdx.x;
    if (bid < 512) {
        int i = bid * 256 + tid;
        Xh[i] = (_Float16)X[i];
        return;
    }
    bid -= 512;
    if (bid < 1600) {   // transpose+cast W[K][N] -> Wt[N][K]
        const float* W; _Float16* Wt; int K, N, b;
        if (bid < 64)        { W = W1; Wt = W1t; K = 64;   N = 1024; b = bid; }
        else if (bid < 1088) { W = W2; Wt = W2t; K = 1024; N = 1024; b = bid - 64; }
        else                 { W = W3; Wt = W3t; K = 1024; N = 512;  b = bid - 1088; }
        int nbx = N / 32;
        int n0 = (b % nbx) * 32, k0 = (b / nbx) * 32;
        int tx = tid & 31, ty = tid >> 5;
#pragma unroll
        for (int i = 0; i < 4; i++)
            tile[ty + i * 8][tx] = W[(size_t)(k0 + ty + i * 8) * N + n0 + tx];
        __syncthreads();
#pragma unroll
        for (int i = 0; i < 4; i++)
            Wt[(size_t)(n0 + ty + i * 8) * K + k0 + tx] = (_Float16)tile[tx][ty + i * 8];
        return;
    }
    bid -= 1600;
    int i = bid * 256 + tid;       // 0 .. 65535
    if (i < 4 * 16 * 64 * 8) {     // s1f: B-frag of S^T, k-axis in pi'-order
        int j = i & 7, lane = (i >> 3) & 63, kk = (i >> 9) & 15, wc = i >> 13;
        int pos = kk * 32 + (lane >> 4) * 8 + j;   // storage k position 0..511
        int pp = pos >> 7, r = pos & 127;
        int hh = r >> 6, r2 = r & 63;
        int lmc = r2 >> 2, t3 = r2 & 3;
        int c = pp * 128 + (hh * 4 + t3) * 16 + lmc;   // pi'^-1
        int m = wc * 16 + (lane & 15);
        s1f[i] = (_Float16)S[m * 512 + c];
    } else {                       // s2f: B-frag of S (k = combos)
        int i2 = i - 4 * 16 * 64 * 8;
        int j = i2 & 7, lane = (i2 >> 3) & 63, c = (i2 >> 9) & 1,
            tt = (i2 >> 10) & 7, wc = i2 >> 13;
        int kc = c * 32 + (lane >> 4) * 8 + j;
        int n = wc * 128 + tt * 16 + (lane & 15);
        s2f[i2] = (_Float16)S[kc * 512 + n];
    }
}

// ---------------- GEMM: out = relu(A[M,K] @ W[K,N] + bias), f16 in, fp32 acc ---
// 64x64 tile, 4 waves, 2 blocks/CU. XOR-swizzled LDS: staging pre-swizzles the
// GLOBAL source chunk (linear gl_lds dest, rule #21); reads XOR by
// ((row>>1)&7)<<3 halves -> frag ds_read_b128 is <=2-way banked (free).
// Blocks with bn >= N: block (x = N/64, y = 0) runs power_64 when Sp != null.
__global__ __launch_bounds__(256, 2) void gemm_relu(
    const _Float16* __restrict__ A, const _Float16* __restrict__ Wt,
    const float* __restrict__ bias, _Float16* __restrict__ outh,
    float* __restrict__ outf, int N, int K,
    const float* __restrict__ Sp, float* __restrict__ tau_g) {
    __shared__ __align__(16) _Float16 As[64 * 32];
    __shared__ __align__(16) _Float16 Bs[64 * 32];
    int tid = threadIdx.x;
    int bm = blockIdx.y * 64;
    int bn = blockIdx.x * 64;
    if (bn >= N) {
        if (blockIdx.y == 0 && Sp) power_64(Sp, tau_g);
        return;
    }
    int w = tid >> 6, l = tid & 63;
    int wr = w >> 1, wc = w & 1;      // wave output tile: rows wr*32, cols wc*32
    int lm = l & 15, q = l >> 4;
    floatx4 acc[2][2] = {};

    // staging: lane l fills phys chunk l of its wave's 16-row region; the
    // logical chunk there is lc = l ^ ((l>>3)&7)  (involution with read XOR)
    int lc = l ^ ((l >> 3) & 7);
    int srow = w * 16 + (lc >> 2), scol = (lc & 3) * 8;
    const _Float16* ag = A + (size_t)(bm + srow) * K + scol;
    const _Float16* bg = Wt + (size_t)(bn + srow) * K + scol;
    _Float16* as = &As[(w * 16) * 32];
    _Float16* bs = &Bs[(w * 16) * 32];
    int sx = ((lm >> 1) & 7) << 3;    // read-side XOR in halves

    for (int k0 = 0; k0 < K; k0 += 32) {
        gl_lds16(ag + k0, as);
        gl_lds16(bg + k0, bs);
        __syncthreads();
        half8 af[2], bf[2];
#pragma unroll
        for (int mt = 0; mt < 2; mt++)
            af[mt] = *(const half8*)&As[((wr * 32 + mt * 16 + lm) * 32 + q * 8) ^ sx];
#pragma unroll
        for (int nt = 0; nt < 2; nt++)
            bf[nt] = *(const half8*)&Bs[((wc * 32 + nt * 16 + lm) * 32 + q * 8) ^ sx];
#pragma unroll
        for (int mt = 0; mt < 2; mt++)
#pragma unroll
            for (int nt = 0; nt < 2; nt++)
                acc[mt][nt] = __builtin_amdgcn_mfma_f32_16x16x32_f16(
                    af[mt], bf[nt], acc[mt][nt], 0, 0, 0);
        __syncthreads();
    }
#pragma unroll
    for (int nt = 0; nt < 2; nt++) {
        int col = bn + wc * 32 + nt * 16 + lm;
        float bv = bias[col];
#pragma unroll
        for (int mt = 0; mt < 2; mt++) {
#pragma unroll
            for (int v = 0; v < 4; v++) {
                int row = bm + wr * 32 + mt * 16 + q * 4 + v;
                float val = fmaxf(acc[mt][nt][v] + bv, 0.f);
                if (outh) outh[(size_t)row * N + col] = (_Float16)val;
                else      outf[(size_t)row * N + col] = val;
            }
        }
    }
}

// ---------------- Delta-form MFMA PDHG, 4 waves, 3 barriers (R16 exact) --------
// Wave p owns columns [p*128, p*128+128). Lane l: lm=l&15, q=l>>4.
// Lane owns batch rows (q&1)*4+v (v=0..3) and columns ((q>>1)*4+t)*16+lm.
// LDS tiles have 8 REAL rows; MFMA A-frags read row (lm&7) -> broadcast pairs,
// out rows 8-15 are live duplicates consumed by q>=2 lanes (tt=4..7 groups).
__global__ __launch_bounds__(256, 1) void pdhg_mfma(
    const float* __restrict__ Zb, const float* __restrict__ Xf,
    const _Float16* __restrict__ s1f, const _Float16* __restrict__ s2f,
    const float* __restrict__ tau_p, float* __restrict__ out) {
    __shared__ __align__(16) _Float16 xb_d[8 * XBS];
    __shared__ __align__(16) _Float16 yl_d[8 * YLS];
    __shared__ __align__(16) float red[8][4];
    int tid = threadIdx.x;
    int p = tid >> 6;                 // wave = column slice
    int l = tid & 63, lm = l & 15, q = l >> 4;
    int lq = lm & 7;                  // 8-row read index (broadcast pairs)
    int qa = q & 1;                   // row group: rows qa*4+v
    int h = q >> 1;                   // column half: tt group h*4..h*4+3
    int b0 = blockIdx.x * 8;

    half8 s1[16], s2[8][2];
#pragma unroll
    for (int k = 0; k < 16; k++)
        s1[k] = *(const half8*)&s1f[((p * 16 + k) * 64 + l) * 8];
#pragma unroll
    for (int u = 0; u < 8; u++)
#pragma unroll
        for (int c = 0; c < 2; c++)
            s2[u][c] = *(const half8*)&s2f[(((p * 8 + u) * 2 + c) * 64 + l) * 8];

    floatx4 z4[4], tz4[4], x4[4], xb4[4], yh4[4], d4[4];
    floatx4 ylo = {}, Bc;
    floatx4 a1p[4] = {};
    floatx4 acc2[8] = {};
    const floatx4 zero4 = {0.f, 0.f, 0.f, 0.f};
    float tau = tau_p[0];
    float sig = tau;

#pragma unroll
    for (int v = 0; v < 4; v++)
        Bc[v] = Xf[(b0 + qa * 4 + v) * 64 + p * 16 + lm];
#pragma unroll
    for (int t = 0; t < 4; t++) {
#pragma unroll
        for (int v = 0; v < 4; v++) {
            float zz = Zb[(size_t)(b0 + qa * 4 + v) * 512 + p * 128 + (h * 4 + t) * 16 + lm];
            z4[t][v] = zz;
            tz4[t][v] = tau - zz;
        }
        x4[t] = zero4; xb4[t] = zero4; yh4[t] = zero4;
    }
    {
        half8 hz = {0, 0, 0, 0, 0, 0, 0, 0};
        for (int i = tid; i < (8 * XBS) / 8; i += 256)
            *(half8*)&xb_d[i * 8] = hz;
        for (int i = tid; i < 8 * YLS; i += 256)
            yl_d[i] = (_Float16)0.f;
    }
    __syncthreads();

#pragma unroll 1
    for (int it = 0; it < NITERS; ++it) {
        // ---- Kx (delta accumulated): a1p += dxbar @ S^T, storage in pi'-order
#pragma unroll
        for (int k = 0; k < 16; k++) {
            half8 ad = *(const half8*)&xb_d[lq * XBS + k * 32 + q * 8];
            a1p[k & 3] = __builtin_amdgcn_mfma_f32_16x16x32_f16(ad, s1[k], a1p[k & 3], 0, 0, 0);
        }
        floatx4 a1 = (a1p[0] + a1p[1]) + (a1p[2] + a1p[3]);
        // ---- y_lo update (rows qa*4+v, combo p*16+lm); q>=2 lanes duplicate
        floatx4 yv = __builtin_elementwise_max(ylo + sig * (a1 - Bc), zero4);
        floatx4 dy = yv - ylo;
        ylo = yv;
        if (q < 2) {
#pragma unroll
            for (int v = 0; v < 4; v++)
                yl_d[(q * 4 + v) * YLS + p * 16 + lm] = (_Float16)dy[v];
        }
        __syncthreads();   // [A]
        // ---- KTy (delta accumulated): acc2 += dy @ S
        half8 a2d[2];
#pragma unroll
        for (int c = 0; c < 2; c++)
            a2d[c] = *(const half8*)&yl_d[lq * YLS + c * 32 + q * 8];
#pragma unroll
        for (int u = 0; u < 8; u++)
#pragma unroll
            for (int c = 0; c < 2; c++)
                acc2[u] = __builtin_amdgcn_mfma_f32_16x16x32_f16(a2d[c], s2[u][c], acc2[u], 0, 0, 0);
        // ---- elementwise: all lanes real (h selects tt group)
        floatx4 pn = {};
#pragma unroll
        for (int t = 0; t < 4; t++) {
            floatx4 accs = h ? acc2[t + 4] : acc2[t];
            yh4[t] = __builtin_elementwise_max(yh4[t] - sig * xb4[t], zero4);
            floatx4 kty = accs - yh4[t];
            floatx4 dd = (x4[t] - tau * kty) + tz4[t];
            d4[t] = dd;
            pn += dd * dd;
        }
        // ---- row-norm reduce: 16 lanes (DPP) + q-partner (xor32) + 4 waves (LDS)
#pragma unroll
        for (int v = 0; v < 4; v++) pn[v] = sum16(pn[v]);
#pragma unroll
        for (int v = 0; v < 4; v++) pn[v] += __shfl_xor(pn[v], 32, 64);
        if (lm == 0 && q < 2) {
#pragma unroll
            for (int v = 0; v < 4; v++) red[q * 4 + v][p] = pn[v];
        }
        __syncthreads();   // [B]
        floatx4 sv;
#pragma unroll
        for (int v = 0; v < 4; v++) {
            floatx4 rr = *(const floatx4*)&red[qa * 4 + v][0];
            float n2 = (rr.x + rr.y) + (rr.z + rr.w);
            sv[v] = fmaxf(1.f - tau * rsqrtf(fmaxf(n2, 1e-24f)), 0.f);
        }
#pragma unroll
        for (int t = 0; t < 4; t++) {
            floatx4 xn = z4[t] + sv * d4[t];
            floatx4 xbn = 2.f * xn - x4[t];
            d4[t] = xbn - xb4[t];   // reuse d4 as delta
            x4[t] = xn;
            xb4[t] = xbn;
        }
        // ---- write delta-xbar f16 at pi'(row, p, h, lm, t): contiguous fp16x4
#pragma unroll
        for (int v = 0; v < 4; v++) {
            fp16x2 p0 = __builtin_amdgcn_cvt_pkrtz(d4[0][v], d4[1][v]);
            fp16x2 p1 = __builtin_amdgcn_cvt_pkrtz(d4[2][v], d4[3][v]);
            fp16x4 hd = __builtin_shufflevector(p0, p1, 0, 1, 2, 3);
            *(fp16x4*)&xb_d[(qa * 4 + v) * XBS + p * 128 + h * 64 + lm * 4] = hd;
        }
        __syncthreads();   // [C]
    }
#pragma unroll
    for (int t = 0; t < 4; t++)
#pragma unroll
        for (int v = 0; v < 4; v++)
            out[(size_t)(b0 + qa * 4 + v) * 512 + p * 128 + (h * 4 + t) * 16 + lm] = x4[t][v];
}

// ---------------------------------------------------------------------------
extern "C" void kernel_launch(void* const* d_in, const int* in_sizes, int n_in,
                              void* d_out, int out_size, void* d_ws, size_t ws_size,
                              hipStream_t stream) {
    const float* X  = (const float*)d_in[0];
    const float* W1 = (const float*)d_in[1];
    const float* b1 = (const float*)d_in[2];
    const float* W2 = (const float*)d_in[3];
    const float* b2 = (const float*)d_in[4];
    const float* W3 = (const float*)d_in[5];
    const float* b3 = (const float*)d_in[6];
    const float* S  = (const float*)d_in[7];
    float* out = (float*)d_out;

    char* ws = (char*)d_ws;
    size_t off = 0;
    auto alloc = [&](size_t bytes) {
        void* p = ws + off;
        off += (bytes + 255) & ~(size_t)255;
        return p;
    };
    _Float16* Xh  = (_Float16*)alloc((size_t)BATCH * 64 * 2);
    _Float16* W1t = (_Float16*)alloc((size_t)64 * 1024 * 2);
    _Float16* W2t = (_Float16*)alloc((size_t)1024 * 1024 * 2);
    _Float16* W3t = (_Float16*)alloc((size_t)1024 * 512 * 2);
    _Float16* H1  = (_Float16*)alloc((size_t)BATCH * 1024 * 2);
    _Float16* H2  = (_Float16*)alloc((size_t)BATCH * 1024 * 2);
    float*    Zb  = (float*)alloc((size_t)BATCH * 512 * 4);
    _Float16* s1f = (_Float16*)alloc((size_t)4 * 16 * 64 * 8 * 2);
    _Float16* s2f = (_Float16*)alloc((size_t)4 * 8 * 2 * 64 * 8 * 2);
    float*    tau = (float*)alloc(256);

    hipLaunchKernelGGL(prep, dim3(2368), dim3(256), 0, stream,
                       X, Xh, W1, W1t, W2, W2t, W3, W3t, S, s1f, s2f);
    hipLaunchKernelGGL(gemm_relu, dim3(16, 32), dim3(256), 0, stream,
                       Xh, W1t, b1, H1, (float*)nullptr, 1024, 64,
                       (const float*)nullptr, (float*)nullptr);
    hipLaunchKernelGGL(gemm_relu, dim3(17, 32), dim3(256), 0, stream,
                       H1, W2t, b2, H2, (float*)nullptr, 1024, 1024, S, tau);
    hipLaunchKernelGGL(gemm_relu, dim3(8, 32), dim3(256), 0, stream,
                       H2, W3t, b3, (_Float16*)nullptr, Zb, 512, 1024,
                       (const float*)nullptr, (float*)nullptr);
    hipLaunchKernelGGL(pdhg_mfma, dim3(BATCH / 8), dim3(256), 0, stream,
                       Zb, X, s1f, s2f, tau, out);
}